// Round 1
// 646.945 us; speedup vs baseline: 1.0902x; 1.0902x over previous
//
#include <hip/hip_runtime.h>

// Multi-scale deformable attention, nearest sampling, zero padding.
// value:             (6, 14960, 8, 32)  f32
// sampling_locations:(6, 40000, 8, 4, 4, 2) f32
// out:               (6, 40000, 256)    f32
//
// Mapping: 8 lanes per (b,q,h); lane owns float4 of D (dg = lane&7).
// Gather per sample = 128B contiguous across the 8 lanes.
//
// This version: explicit 4-phase structure to force memory-level
// parallelism. Previous kernel compiled to VGPR_Count=12 -> fully
// serialized gathers (1 outstanding load/wave), latency-bound at 403us.
// Phases: (1) all loc loads, (2) all 16 offsets+masks, (3) all 16
// gathers issued back-to-back, (4) branchless FMA accumulate.
// __launch_bounds__(256,4): target 4 waves/EU so regalloc allows ~128
// VGPRs instead of starving the load scheduler.

#define BS 6
#define NQ 40000
#define NH 8
#define HD 32
#define NK 14960

__global__ __launch_bounds__(256, 4)
void msda_kernel(const float* __restrict__ value,
                 const float* __restrict__ loc,
                 float* __restrict__ out) {
    constexpr int Wl[4]  = {176, 88, 44, 22};
    constexpr int Hl[4]  = {64, 32, 16, 8};
    constexpr int Off[4] = {0, 11264, 14080, 14784};

    const int tid = blockIdx.x * 256 + threadIdx.x;   // grid sized exactly
    const int dg  = tid & 7;          // which float4 of D
    const int g   = tid >> 3;         // (b*NQ+q)*NH + h
    const int h   = g & 7;
    const int bq  = g >> 3;           // b*NQ + q
    const int b   = bq / NQ;          // compiler emits magic-mul

    const float4* lp = (const float4*)(loc + (size_t)g * 32);

    // u32 byte offset into value for (b, key=0, h, d=dg*4); whole array
    // is 92MB so every sample offset fits in 32 bits.
    const unsigned base_off = (unsigned)b * (NK * NH * HD * 4u)
                            + (unsigned)h * (HD * 4u)
                            + (unsigned)dg * 16u;

    // ---- Phase 1: all sampling locations (8 x float4) ----
    float4 L[8];
    #pragma unroll
    for (int k = 0; k < 8; ++k) L[k] = lp[k];

    // ---- Phase 2: all 16 gather offsets + validity weights ----
    unsigned voff[16];
    float    mwt[16];
    #pragma unroll
    for (int l = 0; l < 4; ++l) {
        const int   W  = Wl[l], Hh = Hl[l], off = Off[l];
        const float wf = (float)W, hf = (float)Hh;
        #pragma unroll
        for (int i = 0; i < 2; ++i) {
            const float4 xy2 = L[l * 2 + i];   // two (x,y) points
            #pragma unroll
            for (int j = 0; j < 2; ++j) {
                const int s = l * 4 + i * 2 + j;
                const float px = j ? xy2.z : xy2.x;
                const float py = j ? xy2.w : xy2.y;
                // Replicate reference FP sequence exactly:
                // g = 2*loc - 1;  x = ((g+1)*w)*0.5 - 0.5;  ix = rint(x)
                const float gx = 2.0f * px - 1.0f;
                const float gy = 2.0f * py - 1.0f;
                const float x  = ((gx + 1.0f) * wf) * 0.5f - 0.5f;
                const float y  = ((gy + 1.0f) * hf) * 0.5f - 0.5f;
                const float fx = rintf(x);   // v_rndne_f32: half-to-even
                const float fy = rintf(y);
                const int ix = (int)fx;
                const int iy = (int)fy;
                const bool valid = (ix >= 0) & (ix < W) & (iy >= 0) & (iy < Hh);
                const int cx = min(max(ix, 0), W - 1);
                const int cy = min(max(iy, 0), Hh - 1);
                const int key = off + cy * W + cx;
                voff[s] = base_off + (unsigned)key * (NH * HD * 4u);
                mwt[s]  = valid ? 1.0f : 0.0f;
            }
        }
    }

    // ---- Phase 3: issue all 16 independent gathers ----
    float4 v[16];
    #pragma unroll
    for (int s = 0; s < 16; ++s) {
        v[s] = *(const float4*)((const char*)value + (size_t)voff[s]);
    }

    // ---- Phase 4: branchless accumulate ----
    // fma(v, 1.0, acc) == acc+v exactly; fma(v, 0.0, acc) == acc exactly,
    // so numerics are identical to the guarded-add reference order.
    float4 acc = make_float4(0.f, 0.f, 0.f, 0.f);
    #pragma unroll
    for (int s = 0; s < 16; ++s) {
        acc.x = fmaf(v[s].x, mwt[s], acc.x);
        acc.y = fmaf(v[s].y, mwt[s], acc.y);
        acc.z = fmaf(v[s].z, mwt[s], acc.z);
        acc.w = fmaf(v[s].w, mwt[s], acc.w);
    }

    // out (b, q, h*HD + d): contiguous float4 per lane, 1KB per wave
    *(float4*)(out + (size_t)g * HD + dg * 4) = acc;
}

extern "C" void kernel_launch(void* const* d_in, const int* in_sizes, int n_in,
                              void* d_out, int out_size, void* d_ws, size_t ws_size,
                              hipStream_t stream) {
    const float* value = (const float*)d_in[0];
    // d_in[1] = value_spatial_shapes (int32) — constants, hardcoded in-kernel
    const float* loc   = (const float*)d_in[2];
    float* out = (float*)d_out;

    // threads = BS*NQ*NH*8 = 15,360,000 = 60000 blocks * 256 (exact)
    msda_kernel<<<60000, 256, 0, stream>>>(value, loc, out);
}

// Round 2
// 620.553 us; speedup vs baseline: 1.1365x; 1.0425x over previous
//
#include <hip/hip_runtime.h>

// Multi-scale deformable attention, nearest sampling, zero padding.
// value:             (6, 14960, 8, 32)  f32
// sampling_locations:(6, 40000, 8, 4, 4, 2) f32
// out:               (6, 40000, 256)    f32
//
// Mapping: 8 lanes per (b,q,h); lane owns float4 of D (dg = lane&7).
// Gather per sample = 128B contiguous across the 8 lanes.
//
// Round-2 changes vs round-1 (which hit 340us/dispatch, VGPR=36):
//  (a) Force MLP=16: one empty asm with 16 "+v" float4 operands pins all
//      gather results live, so the compiler cannot re-serialize the loads
//      (round-1 regalloc chose ~6 outstanding loads).
//  (b) Kill 8x-redundant address math: lane ll of each 8-lane group loads
//      only loc float4 #ll (coalesced 128B/group instead of 8 broadcast
//      loads) and computes its 2 samples' offsets; validity packed in
//      bit0 of the 1024B-aligned key offset; 16 __shfl broadcasts share
//      them group-wide. FP sequence per sample is bit-identical to the
//      reference (computed once, broadcast).

#define BS 6
#define NQ 40000
#define NH 8
#define HD 32
#define NK 14960

typedef float f32x4 __attribute__((ext_vector_type(4)));

__global__ __launch_bounds__(256, 4)
void msda_kernel(const float* __restrict__ value,
                 const float* __restrict__ loc,
                 float* __restrict__ out) {
    const int tid = blockIdx.x * 256 + threadIdx.x;   // grid sized exactly
    const int dg  = tid & 7;          // which float4 of D
    const int g   = tid >> 3;         // (b*NQ+q)*NH + h
    const int h   = g & 7;
    const int bq  = g >> 3;           // b*NQ + q
    const int b   = bq / NQ;          // compiler emits magic-mul

    const int lane = threadIdx.x & 63;
    const int ll   = lane & 7;        // role within the 8-lane group

    // ---- Phase 1: lane ll loads loc float4 #ll of its group ----
    // 8 lanes x 16B = one coalesced 128B segment per group.
    const f32x4 myL = *(const f32x4*)(loc + (size_t)g * 32 + ll * 4);

    // ---- Phase 2a: this lane computes samples s=2*ll and s=2*ll+1 ----
    // sample s = l*4 + i*2 + j ; float4 index l*2+i == ll ; j = s&1
    const int l   = ll >> 1;                      // level
    const int W   = 176 >> l;                     // 176,88,44,22
    const int Hh  = 64  >> l;                     // 64,32,16,8
    const int off = (45056 - (45056 >> (2 * l))) / 3;  // 0,11264,14080,14784
    const float wf = (float)W, hf = (float)Hh;

    int koff[2];
    #pragma unroll
    for (int j = 0; j < 2; ++j) {
        const float px = j ? myL.z : myL.x;
        const float py = j ? myL.w : myL.y;
        // Replicate reference FP sequence exactly:
        // g = 2*loc - 1;  x = ((g+1)*w)*0.5 - 0.5;  ix = rint(x)
        const float gx = 2.0f * px - 1.0f;
        const float gy = 2.0f * py - 1.0f;
        const float x  = ((gx + 1.0f) * wf) * 0.5f - 0.5f;
        const float y  = ((gy + 1.0f) * hf) * 0.5f - 0.5f;
        const float fx = rintf(x);   // v_rndne_f32: half-to-even (np.rint)
        const float fy = rintf(y);
        const int ix = (int)fx;
        const int iy = (int)fy;
        const bool valid = (ix >= 0) & (ix < W) & (iy >= 0) & (iy < Hh);
        const int cx = min(max(ix, 0), W - 1);
        const int cy = min(max(iy, 0), Hh - 1);
        const int key = off + cy * W + cx;
        // key byte-stride is NH*HD*4 = 1024 -> bit0 free for validity
        koff[j] = (key << 10) | (valid ? 1 : 0);
    }

    // ---- Phase 2b: broadcast all 16 sample offsets group-wide ----
    const int srcbase = lane & 56;     // first lane of this group
    int ko[16];
    #pragma unroll
    for (int s = 0; s < 16; ++s)
        ko[s] = __shfl(koff[s & 1], srcbase + (s >> 1), 64);

    // u32 byte offset of (b, key=0, h, d=dg*4); value is 92MB so fits.
    const unsigned base_off = (unsigned)b * (NK * NH * HD * 4u)
                            + (unsigned)h * (HD * 4u)
                            + (unsigned)dg * 16u;

    // ---- Phase 3: all 16 independent gathers in flight ----
    f32x4 v[16];
    #pragma unroll
    for (int s = 0; s < 16; ++s) {
        const unsigned a = base_off + ((unsigned)ko[s] & 0xFFFFFFFEu);
        v[s] = *(const f32x4*)((const char*)value + a);
    }
    // Pin all 16 results live simultaneously: loads must all issue before
    // any accumulate, so regalloc can't re-serialize them (MLP = 16).
    asm volatile(""
        : "+v"(v[0]),  "+v"(v[1]),  "+v"(v[2]),  "+v"(v[3]),
          "+v"(v[4]),  "+v"(v[5]),  "+v"(v[6]),  "+v"(v[7]),
          "+v"(v[8]),  "+v"(v[9]),  "+v"(v[10]), "+v"(v[11]),
          "+v"(v[12]), "+v"(v[13]), "+v"(v[14]), "+v"(v[15]));

    // ---- Phase 4: branchless accumulate ----
    // fma(v, 1.0, acc) == acc+v exactly; fma(v, 0.0, acc) == acc exactly.
    f32x4 acc = {0.f, 0.f, 0.f, 0.f};
    #pragma unroll
    for (int s = 0; s < 16; ++s) {
        const float w = (float)(ko[s] & 1);   // exact 0.0 / 1.0
        acc.x = fmaf(v[s].x, w, acc.x);
        acc.y = fmaf(v[s].y, w, acc.y);
        acc.z = fmaf(v[s].z, w, acc.z);
        acc.w = fmaf(v[s].w, w, acc.w);
    }

    // out (b, q, h*HD + d): contiguous float4 per lane
    *(f32x4*)(out + (size_t)g * HD + dg * 4) = acc;
}

extern "C" void kernel_launch(void* const* d_in, const int* in_sizes, int n_in,
                              void* d_out, int out_size, void* d_ws, size_t ws_size,
                              hipStream_t stream) {
    const float* value = (const float*)d_in[0];
    // d_in[1] = value_spatial_shapes (int32) — constants, hardcoded in-kernel
    const float* loc   = (const float*)d_in[2];
    float* out = (float*)d_out;

    // threads = BS*NQ*NH*8 = 15,360,000 = 60000 blocks * 256 (exact)
    msda_kernel<<<60000, 256, 0, stream>>>(value, loc, out);
}

// Round 3
// 609.083 us; speedup vs baseline: 1.1579x; 1.0188x over previous
//
#include <hip/hip_runtime.h>

// Multi-scale deformable attention, nearest sampling, zero padding.
// value:             (6, 14960, 8, 32)  f32
// sampling_locations:(6, 40000, 8, 4, 4, 2) f32
// out:               (6, 40000, 256)    f32
//
// Mapping: 8 lanes per (b,q,h) group; lane owns float4 of D (dg = lane&7).
// Gather per sample = one 128B line across the 8 lanes.
//
// Round-3 changes vs round-2 (311us/dispatch, VGPR=48, 16 loads in flight):
//  (a) 2 groups per thread -> 32 independent gathers in flight per wave.
//      Tests the hypothesis that we are per-CU miss-concurrency limited
//      (observed 20.6 B/cy/CU ~= 64 lines x 128B / 400cy).
//  (b) Validity packed into a 16-bit mask per group (not 16 live ints):
//      peak live regs ~= v0[16]+v1[16] = 128 VGPRs + masks.
//  (c) Nontemporal loads for loc (streamed once) and nontemporal stores
//      for out: keep L1/L2 capacity for value, whose reuse is the only
//      locality in the kernel. value loads stay cached (L2 hit ~85%).
//  (d) Two adjacent pin-asms (first with "memory" clobber) force all 32
//      loads to issue before the first vmcnt drain.

#define BS 6
#define NQ 40000
#define NH 8
#define HD 32
#define NK 14960

typedef float f32x4 __attribute__((ext_vector_type(4)));

__global__ __launch_bounds__(256, 2)
void msda_kernel(const float* __restrict__ value,
                 const float* __restrict__ loc,
                 float* __restrict__ out) {
    const int t  = threadIdx.x;
    const int ll = t & 7;             // role within the 8-lane group
    const int gi = t >> 3;            // group slot 0..31 in block
    // Block covers 64 consecutive groups: [64*bid, 64*bid+64).
    // 320000 groups per batch, 320000 % 64 == 0 -> g0,g1 share b.
    const int g0 = blockIdx.x * 64 + gi;
    const int g1 = g0 + 32;
    const int h  = g0 & 7;            // (+32 keeps low 3 bits) same for g1
    const int b  = g0 / 320000;       // magic-mul

    const int lane = t & 63;

    // ---- Phase 1: loc loads (nontemporal, read-once stream) ----
    // 8 lanes x 16B = one coalesced 128B segment per group.
    const f32x4 L0 = __builtin_nontemporal_load(
        (const f32x4*)(loc + (size_t)g0 * 32 + ll * 4));
    const f32x4 L1 = __builtin_nontemporal_load(
        (const f32x4*)(loc + (size_t)g1 * 32 + ll * 4));

    // ---- Phase 2a: this lane computes samples s=2*ll, 2*ll+1 of each g ----
    const int l   = ll >> 1;                           // level
    const int W   = 176 >> l;                          // 176,88,44,22
    const int Hh  = 64  >> l;                          // 64,32,16,8
    const int off = (45056 - (45056 >> (2 * l))) / 3;  // 0,11264,14080,14784
    const float wf = (float)W, hf = (float)Hh;

    int k0[2], k1[2];
    #pragma unroll
    for (int grp = 0; grp < 2; ++grp) {
        const f32x4 Lv = grp ? L1 : L0;
        #pragma unroll
        for (int j = 0; j < 2; ++j) {
            const float px = j ? Lv.z : Lv.x;
            const float py = j ? Lv.w : Lv.y;
            // Replicate reference FP sequence exactly:
            // g = 2*loc - 1;  x = ((g+1)*w)*0.5 - 0.5;  ix = rint(x)
            const float gx = 2.0f * px - 1.0f;
            const float gy = 2.0f * py - 1.0f;
            const float x  = ((gx + 1.0f) * wf) * 0.5f - 0.5f;
            const float y  = ((gy + 1.0f) * hf) * 0.5f - 0.5f;
            const float fx = rintf(x);   // v_rndne_f32 (np.rint semantics)
            const float fy = rintf(y);
            const int ix = (int)fx;
            const int iy = (int)fy;
            const bool valid = (ix >= 0) & (ix < W) & (iy >= 0) & (iy < Hh);
            const int cx = min(max(ix, 0), W - 1);
            const int cy = min(max(iy, 0), Hh - 1);
            const int key = off + cy * W + cx;
            // key byte-stride is NH*HD*4 = 1024 -> bit0 carries validity
            const int packed = (key << 10) | (valid ? 1 : 0);
            (grp ? k1 : k0)[j] = packed;
        }
    }

    // ---- Phase 2b: broadcast all 16 offsets of each group + pack masks ----
    const int srcbase = lane & 56;     // first lane of this 8-lane group
    int ko0[16], ko1[16];
    int wm0 = 0, wm1 = 0;
    #pragma unroll
    for (int s = 0; s < 16; ++s) {
        const int a0 = __shfl(k0[s & 1], srcbase + (s >> 1), 64);
        const int a1 = __shfl(k1[s & 1], srcbase + (s >> 1), 64);
        ko0[s] = a0 & ~1;
        ko1[s] = a1 & ~1;
        wm0 |= (a0 & 1) << s;
        wm1 |= (a1 & 1) << s;
    }

    // u32 byte offset of (b, key=0, h, d=ll*4); value is 92MB so fits.
    const unsigned base_off = (unsigned)b * (NK * NH * HD * 4u)
                            + (unsigned)h * (HD * 4u)
                            + (unsigned)ll * 16u;
    const char* vb = (const char*)value;

    // ---- Phase 3: all 32 independent gathers in flight ----
    f32x4 v0[16], v1[16];
    #pragma unroll
    for (int s = 0; s < 16; ++s)
        v0[s] = *(const f32x4*)(vb + (base_off + (unsigned)ko0[s]));
    #pragma unroll
    for (int s = 0; s < 16; ++s)
        v1[s] = *(const f32x4*)(vb + (base_off + (unsigned)ko1[s]));

    // Pin: first asm ("memory") keeps every load above the drain point and
    // forces all 32 issued before v1 is waited on; second pin redefines v0
    // so the consume phase cannot hoist above it.
    asm volatile(""
        : "+v"(v1[0]),  "+v"(v1[1]),  "+v"(v1[2]),  "+v"(v1[3]),
          "+v"(v1[4]),  "+v"(v1[5]),  "+v"(v1[6]),  "+v"(v1[7]),
          "+v"(v1[8]),  "+v"(v1[9]),  "+v"(v1[10]), "+v"(v1[11]),
          "+v"(v1[12]), "+v"(v1[13]), "+v"(v1[14]), "+v"(v1[15])
        :
        : "memory");
    asm volatile(""
        : "+v"(v0[0]),  "+v"(v0[1]),  "+v"(v0[2]),  "+v"(v0[3]),
          "+v"(v0[4]),  "+v"(v0[5]),  "+v"(v0[6]),  "+v"(v0[7]),
          "+v"(v0[8]),  "+v"(v0[9]),  "+v"(v0[10]), "+v"(v0[11]),
          "+v"(v0[12]), "+v"(v0[13]), "+v"(v0[14]), "+v"(v0[15]));

    // ---- Phase 4: branchless accumulate (same FP order as reference) ----
    f32x4 acc0 = {0.f, 0.f, 0.f, 0.f};
    #pragma unroll
    for (int s = 0; s < 16; ++s) {
        const float w = (float)((wm0 >> s) & 1);   // exact 0.0 / 1.0
        acc0.x = fmaf(v0[s].x, w, acc0.x);
        acc0.y = fmaf(v0[s].y, w, acc0.y);
        acc0.z = fmaf(v0[s].z, w, acc0.z);
        acc0.w = fmaf(v0[s].w, w, acc0.w);
    }
    f32x4 acc1 = {0.f, 0.f, 0.f, 0.f};
    #pragma unroll
    for (int s = 0; s < 16; ++s) {
        const float w = (float)((wm1 >> s) & 1);
        acc1.x = fmaf(v1[s].x, w, acc1.x);
        acc1.y = fmaf(v1[s].y, w, acc1.y);
        acc1.z = fmaf(v1[s].z, w, acc1.z);
        acc1.w = fmaf(v1[s].w, w, acc1.w);
    }

    // out (b, q, h*HD + d): contiguous 128B per group, write-once stream
    __builtin_nontemporal_store(acc0, (f32x4*)(out + (size_t)g0 * HD + ll * 4));
    __builtin_nontemporal_store(acc1, (f32x4*)(out + (size_t)g1 * HD + ll * 4));
}

extern "C" void kernel_launch(void* const* d_in, const int* in_sizes, int n_in,
                              void* d_out, int out_size, void* d_ws, size_t ws_size,
                              hipStream_t stream) {
    const float* value = (const float*)d_in[0];
    // d_in[1] = value_spatial_shapes (int32) — constants, hardcoded in-kernel
    const float* loc   = (const float*)d_in[2];
    float* out = (float*)d_out;

    // threads = BS*NQ*NH*8/2 = 7,680,000 = 30000 blocks * 256 (exact)
    msda_kernel<<<30000, 256, 0, stream>>>(value, loc, out);
}

// Round 4
// 607.457 us; speedup vs baseline: 1.1610x; 1.0027x over previous
//
#include <hip/hip_runtime.h>

// Multi-scale deformable attention, nearest sampling, zero padding.
// value:             (6, 14960, 8, 32)  f32
// sampling_locations:(6, 40000, 8, 4, 4, 2) f32
// out:               (6, 40000, 256)    f32
//
// Mapping: 8 lanes per (b,q,h) group; lane owns float4 of D (dg = lane&7).
// Gather per sample = one 128B line across the 8 lanes.
//
// Round-4 changes vs round-3 (287us/dispatch, FETCH=840MB, ~22 B/cy/CU):
//  (a) (b,h)-major block decomposition with XCD pinning. Per-(b,h) value
//      footprint = 14960 keys x 128B = 1.9MB < 4MB L2/XCD; level-3 slice
//      22.5KB < 32KB L1. xcd = blockIdx.x & 7 selects h (hardware
//      round-robins blockIdx across XCDs); seq = blockIdx.x >> 3 walks
//      (b, query-chunk) so all CUs of an XCD hammer the SAME (b,h) for
//      ~625 consecutive blocks -> value gathers become L2/L1 hits.
//      Round-3 showed per-CU gather throughput pinned at ~22 B/cy
//      (miss-queue x ~400cy L3 latency); halving latency is the only
//      remaining lever. Wrong XCD guess only costs locality, not
//      correctness.
//  (b) Everything else kept from round-3: 2 queries/thread (32 gathers in
//      flight), validity in bit0 of 1024B-aligned key offsets, dedup'd
//      address math + __shfl broadcast, nontemporal loc/out, pin-asms.

#define BS 6
#define NQ 40000
#define NH 8
#define HD 32
#define NK 14960

typedef float f32x4 __attribute__((ext_vector_type(4)));

__global__ __launch_bounds__(256, 2)
void msda_kernel(const float* __restrict__ value,
                 const float* __restrict__ loc,
                 float* __restrict__ out) {
    const int t  = threadIdx.x;
    const int ll = t & 7;             // role within the 8-lane group
    const int gi = t >> 3;            // group slot 0..31 in block

    // ---- (b,h)-major decomposition, XCD-pinned ----
    // grid = 30000 = 8 xcd * (6 b * 625 qchunks); 625 = 40000/64
    const int xcd = blockIdx.x & 7;
    const int seq = blockIdx.x >> 3;      // 0..3749
    const int b   = seq / 625;            // magic-mul
    const int qc  = seq - b * 625;
    const int h   = xcd;
    const int q0  = qc * 64 + gi;         // this thread's two queries
    const int q1  = q0 + 32;
    // flat group ids (b*NQ+q)*NH + h for loc/out addressing
    const int g0  = (b * NQ + q0) * NH + h;
    const int g1  = g0 + 32 * NH;

    const int lane = t & 63;

    // ---- Phase 1: loc loads (nontemporal, read-once stream) ----
    // 8 lanes x 16B = one coalesced 128B segment per group.
    const f32x4 L0 = __builtin_nontemporal_load(
        (const f32x4*)(loc + (size_t)g0 * 32 + ll * 4));
    const f32x4 L1 = __builtin_nontemporal_load(
        (const f32x4*)(loc + (size_t)g1 * 32 + ll * 4));

    // ---- Phase 2a: this lane computes samples s=2*ll, 2*ll+1 of each q ----
    const int l   = ll >> 1;                           // level
    const int W   = 176 >> l;                          // 176,88,44,22
    const int Hh  = 64  >> l;                          // 64,32,16,8
    const int off = (45056 - (45056 >> (2 * l))) / 3;  // 0,11264,14080,14784
    const float wf = (float)W, hf = (float)Hh;

    int k0[2], k1[2];
    #pragma unroll
    for (int grp = 0; grp < 2; ++grp) {
        const f32x4 Lv = grp ? L1 : L0;
        #pragma unroll
        for (int j = 0; j < 2; ++j) {
            const float px = j ? Lv.z : Lv.x;
            const float py = j ? Lv.w : Lv.y;
            // Replicate reference FP sequence exactly:
            // g = 2*loc - 1;  x = ((g+1)*w)*0.5 - 0.5;  ix = rint(x)
            const float gx = 2.0f * px - 1.0f;
            const float gy = 2.0f * py - 1.0f;
            const float x  = ((gx + 1.0f) * wf) * 0.5f - 0.5f;
            const float y  = ((gy + 1.0f) * hf) * 0.5f - 0.5f;
            const float fx = rintf(x);   // v_rndne_f32 (np.rint semantics)
            const float fy = rintf(y);
            const int ix = (int)fx;
            const int iy = (int)fy;
            const bool valid = (ix >= 0) & (ix < W) & (iy >= 0) & (iy < Hh);
            const int cx = min(max(ix, 0), W - 1);
            const int cy = min(max(iy, 0), Hh - 1);
            const int key = off + cy * W + cx;
            // key byte-stride is NH*HD*4 = 1024 -> bit0 carries validity
            const int packed = (key << 10) | (valid ? 1 : 0);
            (grp ? k1 : k0)[j] = packed;
        }
    }

    // ---- Phase 2b: broadcast all 16 offsets of each query + pack masks ----
    const int srcbase = lane & 56;     // first lane of this 8-lane group
    int ko0[16], ko1[16];
    int wm0 = 0, wm1 = 0;
    #pragma unroll
    for (int s = 0; s < 16; ++s) {
        const int a0 = __shfl(k0[s & 1], srcbase + (s >> 1), 64);
        const int a1 = __shfl(k1[s & 1], srcbase + (s >> 1), 64);
        ko0[s] = a0 & ~1;
        ko1[s] = a1 & ~1;
        wm0 |= (a0 & 1) << s;
        wm1 |= (a1 & 1) << s;
    }

    // u32 byte offset of (b, key=0, h, d=ll*4); value is 92MB so fits.
    const unsigned base_off = (unsigned)b * (NK * NH * HD * 4u)
                            + (unsigned)h * (HD * 4u)
                            + (unsigned)ll * 16u;
    const char* vb = (const char*)value;

    // ---- Phase 3: all 32 independent gathers in flight ----
    f32x4 v0[16], v1[16];
    #pragma unroll
    for (int s = 0; s < 16; ++s)
        v0[s] = *(const f32x4*)(vb + (base_off + (unsigned)ko0[s]));
    #pragma unroll
    for (int s = 0; s < 16; ++s)
        v1[s] = *(const f32x4*)(vb + (base_off + (unsigned)ko1[s]));

    // Pin: first asm ("memory") keeps every load above the drain point and
    // forces all 32 issued before v1 is waited on; second pin redefines v0
    // so the consume phase cannot hoist above it.
    asm volatile(""
        : "+v"(v1[0]),  "+v"(v1[1]),  "+v"(v1[2]),  "+v"(v1[3]),
          "+v"(v1[4]),  "+v"(v1[5]),  "+v"(v1[6]),  "+v"(v1[7]),
          "+v"(v1[8]),  "+v"(v1[9]),  "+v"(v1[10]), "+v"(v1[11]),
          "+v"(v1[12]), "+v"(v1[13]), "+v"(v1[14]), "+v"(v1[15])
        :
        : "memory");
    asm volatile(""
        : "+v"(v0[0]),  "+v"(v0[1]),  "+v"(v0[2]),  "+v"(v0[3]),
          "+v"(v0[4]),  "+v"(v0[5]),  "+v"(v0[6]),  "+v"(v0[7]),
          "+v"(v0[8]),  "+v"(v0[9]),  "+v"(v0[10]), "+v"(v0[11]),
          "+v"(v0[12]), "+v"(v0[13]), "+v"(v0[14]), "+v"(v0[15]));

    // ---- Phase 4: branchless accumulate (same FP order as reference) ----
    f32x4 acc0 = {0.f, 0.f, 0.f, 0.f};
    #pragma unroll
    for (int s = 0; s < 16; ++s) {
        const float w = (float)((wm0 >> s) & 1);   // exact 0.0 / 1.0
        acc0.x = fmaf(v0[s].x, w, acc0.x);
        acc0.y = fmaf(v0[s].y, w, acc0.y);
        acc0.z = fmaf(v0[s].z, w, acc0.z);
        acc0.w = fmaf(v0[s].w, w, acc0.w);
    }
    f32x4 acc1 = {0.f, 0.f, 0.f, 0.f};
    #pragma unroll
    for (int s = 0; s < 16; ++s) {
        const float w = (float)((wm1 >> s) & 1);
        acc1.x = fmaf(v1[s].x, w, acc1.x);
        acc1.y = fmaf(v1[s].y, w, acc1.y);
        acc1.z = fmaf(v1[s].z, w, acc1.z);
        acc1.w = fmaf(v1[s].w, w, acc1.w);
    }

    // out (b, q, h*HD + d): one 128B segment per group, write-once stream
    __builtin_nontemporal_store(acc0, (f32x4*)(out + (size_t)g0 * HD + ll * 4));
    __builtin_nontemporal_store(acc1, (f32x4*)(out + (size_t)g1 * HD + ll * 4));
}

extern "C" void kernel_launch(void* const* d_in, const int* in_sizes, int n_in,
                              void* d_out, int out_size, void* d_ws, size_t ws_size,
                              hipStream_t stream) {
    const float* value = (const float*)d_in[0];
    // d_in[1] = value_spatial_shapes (int32) — constants, hardcoded in-kernel
    const float* loc   = (const float*)d_in[2];
    float* out = (float*)d_out;

    // grid = 8 xcd * 6 b * 625 qchunks = 30000 blocks * 256 threads
    // (2 queries per thread: 30000*256*2*8 lanes == 6*40000*8 groups * 8)
    msda_kernel<<<30000, 256, 0, stream>>>(value, loc, out);
}